// Round 8
// baseline (556.001 us; speedup 1.0000x reference)
//
#include <hip/hip_runtime.h>
#include <hip/hip_bf16.h>

// AttentionAggregator: fused one-pass kernel, round 8.
// Anchor = R4 (288us, known-good). ONE delta: layer-2 matvec h1 delivery via
// wave-private LDS bounce (4 ds_write + 64 uniform broadcast ds_read_b128 per
// pair) instead of 512 v_readlane -> ~440 fewer VALU inst/pair (~35% of
// issue). Identical fp order. NO waves_per_eu attribute (R6/R7's spill
// trigger), launch_bounds(256,4) as in R4.

namespace {
constexpr float kEps = 1e-5f;
constexpr float kLn3 = 1.0986122886681098f;  // ln(3)
}

__device__ __forceinline__ float lane_bcast(float v, int srclane) {
    return __uint_as_float(__builtin_amdgcn_readlane(__float_as_uint(v), srclane));
}

template <int CTRL>
__device__ __forceinline__ float dpp_add(float x) {
    int s = __builtin_amdgcn_update_dpp(0, __float_as_int(x), CTRL, 0xF, 0xF, true);
    return x + __int_as_float(s);
}

// Full 64-lane sum on the VALU pipe; total lands in lane 63.
__device__ __forceinline__ float dpp_sum63(float x) {
    x = dpp_add<0x111>(x);  // row_shr:1
    x = dpp_add<0x112>(x);  // row_shr:2
    x = dpp_add<0x114>(x);  // row_shr:4
    x = dpp_add<0x118>(x);  // row_shr:8
    x = dpp_add<0x142>(x);  // row_bcast:15
    x = dpp_add<0x143>(x);  // row_bcast:31
    return x;
}

__device__ __forceinline__ float dot4(float4 a, float4 b) {
    return fmaf(a.w, b.w, fmaf(a.z, b.z, fmaf(a.y, b.y, a.x * b.x)));
}

// tanh(x) = 1 - 2/(e^{2x}+1); ~1e-6 rel err, saturates correctly.
__device__ __forceinline__ float fast_tanh(float x) {
    const float t = __expf(2.0f * x);
    return fmaf(-2.0f, __builtin_amdgcn_rcpf(t + 1.0f), 1.0f);
}

__global__ __launch_bounds__(256, 4) void agg_fused(
    const float* __restrict__ x, const float* __restrict__ mask,
    const float* __restrict__ attn_w, const float* __restrict__ attn_b,
    const float* __restrict__ w1, const float* __restrict__ b1,
    const float* __restrict__ g1, const float* __restrict__ be1,
    const float* __restrict__ m1, const float* __restrict__ v1,
    const float* __restrict__ w2, const float* __restrict__ b2,
    const float* __restrict__ g2, const float* __restrict__ be2,
    const float* __restrict__ m2, const float* __restrict__ v2,
    const float* __restrict__ w3, const float* __restrict__ b3,
    float* __restrict__ out_ret, float* __restrict__ out_w,
    float* __restrict__ out_cls, int bpw)
{
    // w2 tile, slot-XOR swizzled: element chunk (j, c) lives at
    // w2s4[j*32 + (c ^ (j&7))] -> a wave-wide ds_read_b128 of one chunk
    // column hits the structural 8-pass minimum.
    __shared__ float4 w2s4[64 * 32];
    // wave-private h1 bounce rows: [wave][u/v][128] floats (4 KB)
    __shared__ float h1s[4][2][128];

    const int tid  = threadIdx.x;
    const int lane = tid & 63;
    const int wiw  = tid >> 6;
    const int wid  = blockIdx.x * 4 + wiw;

    // ---- stage w2 into LDS (once per block, coalesced) ----
    {
        const float4* w2v = reinterpret_cast<const float4*>(w2);
#pragma unroll
        for (int p = 0; p < 8; ++p) {
            const int idx = tid + p * 256;           // = j*32 + c
            const int j = idx >> 5, c = idx & 31;
            w2s4[j * 32 + (c ^ (j & 7))] = w2v[idx];
        }
    }
    __syncthreads();

    // ---- loop-invariant per-lane parameters (BN folded to fma consts) ----
    const float4 aw  = *reinterpret_cast<const float4*>(attn_w + lane * 4);
    const float  ab  = attn_b[0];
    const float4 w1a = *reinterpret_cast<const float4*>(w1 + lane * 4);
    const float4 w1b = *reinterpret_cast<const float4*>(w1 + (lane + 64) * 4);
    const float  b1a = b1[lane], b1b = b1[lane + 64];
    const float  c1a = g1[lane] * (1.0f / sqrtf(v1[lane] + kEps));
    const float  c1b = g1[lane + 64] * (1.0f / sqrtf(v1[lane + 64] + kEps));
    const float  c0a = be1[lane] - m1[lane] * c1a;
    const float  c0b = be1[lane + 64] - m1[lane + 64] * c1b;
    const float  b2j = b2[lane];

    // head fold: cls = [ sum_j alpha_j*ReLU(pre_j) > thrp ]
    float alpha, thrp;
    {
        const float wdj = w3[64 + lane] - w3[lane];
        const float c12 = g2[lane] * (1.0f / sqrtf(v2[lane] + kEps));
        const float c02 = be2[lane] - m2[lane] * c12;
        alpha = wdj * c12;
        const float C = lane_bcast(dpp_sum63(wdj * c02), 63);
        thrp = kLn3 - (b3[1] - b3[0]) - C;
    }

    // 8 swizzled row base indices for this lane's w2 row (float4 units).
    int wofs[8];
#pragma unroll
    for (int m = 0; m < 8; ++m) wofs[m] = lane * 32 + (m ^ (lane & 7));

    const int b0 = wid * bpw;
    const float* xp = x    + (size_t)b0 * 1024 + lane * 4;
    const float* mp = mask + (size_t)b0 * 4;
    float*       rp = out_ret + (size_t)b0 * 256 + lane * 4;
    float*       wp = out_w   + (size_t)b0 * 4;
    float*       cp = out_cls + b0;

#pragma unroll 1
    for (int i = 0; i < bpw; i += 2) {
        // Stop LICM/CSE from hoisting the loop-invariant LDS w2 reads out of
        // the loop into 128 registers (spill hazard seen in R3).
        asm volatile("" ::: "memory");

        // ---- load pair of batches u=i, v=i+1 (8 coalesced b128 + 2 masks) ----
        const float4 xu0 = *reinterpret_cast<const float4*>(xp + 0);
        const float4 xu1 = *reinterpret_cast<const float4*>(xp + 256);
        const float4 xu2 = *reinterpret_cast<const float4*>(xp + 512);
        const float4 xu3 = *reinterpret_cast<const float4*>(xp + 768);
        const float4 xv0 = *reinterpret_cast<const float4*>(xp + 1024);
        const float4 xv1 = *reinterpret_cast<const float4*>(xp + 1280);
        const float4 xv2 = *reinterpret_cast<const float4*>(xp + 1536);
        const float4 xv3 = *reinterpret_cast<const float4*>(xp + 1792);
        const float4 mku = *reinterpret_cast<const float4*>(mp);
        const float4 mkv = *reinterpret_cast<const float4*>(mp + 4);

        // ---- attention scores (8 independent DPP chains, good ILP) ----
        float ru0 = dpp_sum63(dot4(xu0, aw));
        float ru1 = dpp_sum63(dot4(xu1, aw));
        float ru2 = dpp_sum63(dot4(xu2, aw));
        float ru3 = dpp_sum63(dot4(xu3, aw));
        float rv0 = dpp_sum63(dot4(xv0, aw));
        float rv1 = dpp_sum63(dot4(xv1, aw));
        float rv2 = dpp_sum63(dot4(xv2, aw));
        float rv3 = dpp_sum63(dot4(xv3, aw));
        const float au0 = fast_tanh(lane_bcast(ru0, 63) + ab) + mku.x;
        const float au1 = fast_tanh(lane_bcast(ru1, 63) + ab) + mku.y;
        const float au2 = fast_tanh(lane_bcast(ru2, 63) + ab) + mku.z;
        const float au3 = fast_tanh(lane_bcast(ru3, 63) + ab) + mku.w;
        const float av0 = fast_tanh(lane_bcast(rv0, 63) + ab) + mkv.x;
        const float av1 = fast_tanh(lane_bcast(rv1, 63) + ab) + mkv.y;
        const float av2 = fast_tanh(lane_bcast(rv2, 63) + ab) + mkv.z;
        const float av3 = fast_tanh(lane_bcast(rv3, 63) + ab) + mkv.w;

        // ---- softmax over 4 members, each batch ----
        const float umax = fmaxf(fmaxf(au0, au1), fmaxf(au2, au3));
        const float eu0 = __expf(au0 - umax), eu1 = __expf(au1 - umax);
        const float eu2 = __expf(au2 - umax), eu3 = __expf(au3 - umax);
        const float urs = __builtin_amdgcn_rcpf(((eu0 + eu1) + eu2) + eu3);
        const float wtu0 = eu0 * urs, wtu1 = eu1 * urs, wtu2 = eu2 * urs, wtu3 = eu3 * urs;

        const float vmax = fmaxf(fmaxf(av0, av1), fmaxf(av2, av3));
        const float ev0 = __expf(av0 - vmax), ev1 = __expf(av1 - vmax);
        const float ev2 = __expf(av2 - vmax), ev3 = __expf(av3 - vmax);
        const float vrs = __builtin_amdgcn_rcpf(((ev0 + ev1) + ev2) + ev3);
        const float wtv0 = ev0 * vrs, wtv1 = ev1 * vrs, wtv2 = ev2 * vrs, wtv3 = ev3 * vrs;

        // ---- layer 1: h1 = fma(relu(wf . w1row + b1), c1, c0) ----
        float pu = fmaf(wtu3, w1a.w, fmaf(wtu2, w1a.z, fmaf(wtu1, w1a.y, wtu0 * w1a.x))) + b1a;
        const float h1uA = fmaf(fmaxf(pu, 0.0f), c1a, c0a);
        pu = fmaf(wtu3, w1b.w, fmaf(wtu2, w1b.z, fmaf(wtu1, w1b.y, wtu0 * w1b.x))) + b1b;
        const float h1uB = fmaf(fmaxf(pu, 0.0f), c1b, c0b);
        float pv = fmaf(wtv3, w1a.w, fmaf(wtv2, w1a.z, fmaf(wtv1, w1a.y, wtv0 * w1a.x))) + b1a;
        const float h1vA = fmaf(fmaxf(pv, 0.0f), c1a, c0a);
        pv = fmaf(wtv3, w1b.w, fmaf(wtv2, w1b.z, fmaf(wtv1, w1b.y, wtv0 * w1b.x))) + b1b;
        const float h1vB = fmaf(fmaxf(pv, 0.0f), c1b, c0b);

        // ---- layer 2 matvec for BOTH batches. h1 bounced through a
        // wave-private LDS row; read back as uniform-address (broadcast,
        // conflict-free) ds_read_b128 -> replaces 512 v_readlane/pair. ----
        h1s[wiw][0][lane]      = h1uA;
        h1s[wiw][0][lane + 64] = h1uB;
        h1s[wiw][1][lane]      = h1vA;
        h1s[wiw][1][lane + 64] = h1vB;

        float accu0 = 0.0f, accu1 = 0.0f, accu2 = 0.0f, accu3 = 0.0f;
        float accv0 = 0.0f, accv1 = 0.0f, accv2 = 0.0f, accv3 = 0.0f;
#pragma unroll
        for (int c = 0; c < 32; ++c) {
            const float4 wv = w2s4[wofs[c & 7] + (c >> 3) * 8];
            const float4 hu = *reinterpret_cast<const float4*>(&h1s[wiw][0][c * 4]);
            const float4 hv = *reinterpret_cast<const float4*>(&h1s[wiw][1][c * 4]);
            accu0 = fmaf(hu.x, wv.x, accu0);
            accu1 = fmaf(hu.y, wv.y, accu1);
            accu2 = fmaf(hu.z, wv.z, accu2);
            accu3 = fmaf(hu.w, wv.w, accu3);
            accv0 = fmaf(hv.x, wv.x, accv0);
            accv1 = fmaf(hv.y, wv.y, accv1);
            accv2 = fmaf(hv.z, wv.z, accv2);
            accv3 = fmaf(hv.w, wv.w, accv3);
        }
        const float preU = ((accu0 + accu1) + (accu2 + accu3)) + b2j;
        const float preV = ((accv0 + accv1) + (accv2 + accv3)) + b2j;
        float dzu = dpp_sum63(alpha * fmaxf(preU, 0.0f));
        float dzv = dpp_sum63(alpha * fmaxf(preV, 0.0f));
        const int clsU = (lane_bcast(dzu, 63) > thrp) ? 1 : 0;
        const int clsV = (lane_bcast(dzv, 63) > thrp) ? 1 : 0;

        // ---- batch u: argmax, pooling, store ----
        {
            int midx = 0; float mval = wtu0;
            if (wtu1 > mval) { mval = wtu1; midx = 1; }
            if (wtu2 > mval) { mval = wtu2; midx = 2; }
            if (wtu3 > mval) { mval = wtu3; midx = 3; }
            const float4 g01 = (midx == 1) ? xu1 : xu0;
            const float4 g23 = (midx == 3) ? xu3 : xu2;
            const float4 gth = (midx >= 2) ? g23 : g01;
            float4 pl;
            pl.x = fmaf(wtu3, xu3.x, fmaf(wtu2, xu2.x, fmaf(wtu1, xu1.x, wtu0 * xu0.x)));
            pl.y = fmaf(wtu3, xu3.y, fmaf(wtu2, xu2.y, fmaf(wtu1, xu1.y, wtu0 * xu0.y)));
            pl.z = fmaf(wtu3, xu3.z, fmaf(wtu2, xu2.z, fmaf(wtu1, xu1.z, wtu0 * xu0.z)));
            pl.w = fmaf(wtu3, xu3.w, fmaf(wtu2, xu2.w, fmaf(wtu1, xu1.w, wtu0 * xu0.w)));
            const float4 ret = (clsU == 1) ? gth : pl;
            *reinterpret_cast<float4*>(rp + (size_t)i * 256) = ret;
            if (lane == 0) {
                *reinterpret_cast<float4*>(wp + (size_t)i * 4) =
                    make_float4(wtu0, wtu1, wtu2, wtu3);
                cp[i] = (float)clsU;
            }
        }
        // ---- batch v: argmax, pooling, store ----
        {
            int midx = 0; float mval = wtv0;
            if (wtv1 > mval) { mval = wtv1; midx = 1; }
            if (wtv2 > mval) { mval = wtv2; midx = 2; }
            if (wtv3 > mval) { mval = wtv3; midx = 3; }
            const float4 g01 = (midx == 1) ? xv1 : xv0;
            const float4 g23 = (midx == 3) ? xv3 : xv2;
            const float4 gth = (midx >= 2) ? g23 : g01;
            float4 pl;
            pl.x = fmaf(wtv3, xv3.x, fmaf(wtv2, xv2.x, fmaf(wtv1, xv1.x, wtv0 * xv0.x)));
            pl.y = fmaf(wtv3, xv3.y, fmaf(wtv2, xv2.y, fmaf(wtv1, xv1.y, wtv0 * xv0.y)));
            pl.z = fmaf(wtv3, xv3.z, fmaf(wtv2, xv2.z, fmaf(wtv1, xv1.z, wtv0 * xv0.z)));
            pl.w = fmaf(wtv3, xv3.w, fmaf(wtv2, xv2.w, fmaf(wtv1, xv1.w, wtv0 * xv0.w)));
            const float4 ret = (clsV == 1) ? gth : pl;
            *reinterpret_cast<float4*>(rp + (size_t)(i + 1) * 256) = ret;
            if (lane == 0) {
                *reinterpret_cast<float4*>(wp + (size_t)(i + 1) * 4) =
                    make_float4(wtv0, wtv1, wtv2, wtv3);
                cp[i + 1] = (float)clsV;
            }
        }

        xp += 2048;
        mp += 8;
    }
}

extern "C" void kernel_launch(void* const* d_in, const int* in_sizes, int n_in,
                              void* d_out, int out_size, void* d_ws, size_t ws_size,
                              hipStream_t stream) {
    const float* x      = (const float*)d_in[0];
    const float* mask   = (const float*)d_in[1];
    const float* attn_w = (const float*)d_in[2];
    const float* attn_b = (const float*)d_in[3];
    const float* w1     = (const float*)d_in[4];
    const float* b1     = (const float*)d_in[5];
    const float* g1     = (const float*)d_in[6];
    const float* be1    = (const float*)d_in[7];
    const float* m1     = (const float*)d_in[8];
    const float* v1     = (const float*)d_in[9];
    const float* w2     = (const float*)d_in[10];
    const float* b2     = (const float*)d_in[11];
    const float* g2     = (const float*)d_in[12];
    const float* be2    = (const float*)d_in[13];
    const float* m2     = (const float*)d_in[14];
    const float* v2     = (const float*)d_in[15];
    const float* w3     = (const float*)d_in[16];
    const float* b3     = (const float*)d_in[17];

    float* out = (float*)d_out;
    float* out_ret = out;                         // [B, 256]
    float* out_w   = out + (size_t)262144 * 256;  // [B, 4, 1]
    float* out_cls = out_w + (size_t)262144 * 4;  // [B]

    const int threads = 256;                      // 4 waves/block
    const int blocks  = 4096;                     // 16384 waves total
    const int waves   = blocks * (threads / 64);
    const int bpw     = 262144 / waves;           // 16 batches/wave (8 pairs)

    agg_fused<<<blocks, threads, 0, stream>>>(
        x, mask, attn_w, attn_b, w1, b1, g1, be1, m1, v1,
        w2, b2, g2, be2, m2, v2, w3, b3,
        out_ret, out_w, out_cls, bpw);
}

// Round 9
// 288.331 us; speedup vs baseline: 1.9283x; 1.9283x over previous
//
#include <hip/hip_runtime.h>
#include <hip/hip_bf16.h>

// AttentionAggregator: fused one-pass kernel, round 9 = exact revert to R4
// (288us, best measured). R5-R8 all regressed (2.2-3.7x) via register-
// allocator spill interactions invisible through this interface; R4 is the
// empirically stable optimum of this structure family.
//  - 4 waves/block, __launch_bounds__(256, 4): 4 blocks/CU, VGPR cap 128.
//  - w2 (64x128 f32) in slot-XOR-swizzled LDS, ds_read_b128.
//  - pair-processing: one w2 chunk read feeds 8 fmacs (2 batches x 4).
//  - h1 broadcast via v_readlane on the VALU pipe.
//  - BN folded; head folded to one reduction: cls = [sum a_j ReLU(pre_j) > thr'].
//  - loop-top asm "memory" clobber prevents LICM of the LDS w2 tile (R3 spill).

namespace {
constexpr float kEps = 1e-5f;
constexpr float kLn3 = 1.0986122886681098f;  // ln(3)
}

__device__ __forceinline__ float lane_bcast(float v, int srclane) {
    return __uint_as_float(__builtin_amdgcn_readlane(__float_as_uint(v), srclane));
}

template <int CTRL>
__device__ __forceinline__ float dpp_add(float x) {
    int s = __builtin_amdgcn_update_dpp(0, __float_as_int(x), CTRL, 0xF, 0xF, true);
    return x + __int_as_float(s);
}

// Full 64-lane sum on the VALU pipe; total lands in lane 63.
__device__ __forceinline__ float dpp_sum63(float x) {
    x = dpp_add<0x111>(x);  // row_shr:1
    x = dpp_add<0x112>(x);  // row_shr:2
    x = dpp_add<0x114>(x);  // row_shr:4
    x = dpp_add<0x118>(x);  // row_shr:8
    x = dpp_add<0x142>(x);  // row_bcast:15
    x = dpp_add<0x143>(x);  // row_bcast:31
    return x;
}

__device__ __forceinline__ float dot4(float4 a, float4 b) {
    return fmaf(a.w, b.w, fmaf(a.z, b.z, fmaf(a.y, b.y, a.x * b.x)));
}

// tanh(x) = 1 - 2/(e^{2x}+1); ~1e-6 rel err, saturates correctly.
__device__ __forceinline__ float fast_tanh(float x) {
    const float t = __expf(2.0f * x);
    return fmaf(-2.0f, __builtin_amdgcn_rcpf(t + 1.0f), 1.0f);
}

__global__ __launch_bounds__(256, 4) void agg_fused(
    const float* __restrict__ x, const float* __restrict__ mask,
    const float* __restrict__ attn_w, const float* __restrict__ attn_b,
    const float* __restrict__ w1, const float* __restrict__ b1,
    const float* __restrict__ g1, const float* __restrict__ be1,
    const float* __restrict__ m1, const float* __restrict__ v1,
    const float* __restrict__ w2, const float* __restrict__ b2,
    const float* __restrict__ g2, const float* __restrict__ be2,
    const float* __restrict__ m2, const float* __restrict__ v2,
    const float* __restrict__ w3, const float* __restrict__ b3,
    float* __restrict__ out_ret, float* __restrict__ out_w,
    float* __restrict__ out_cls, int bpw)
{
    // w2 tile, slot-XOR swizzled: element chunk (j, c) lives at
    // w2s4[j*32 + (c ^ (j&7))] -> a wave-wide ds_read_b128 of one chunk
    // column hits all 32 banks at the structural minimum.
    __shared__ float4 w2s4[64 * 32];

    const int tid  = threadIdx.x;
    const int lane = tid & 63;
    const int wid  = blockIdx.x * 4 + (tid >> 6);

    // ---- stage w2 into LDS (once per block, coalesced) ----
    {
        const float4* w2v = reinterpret_cast<const float4*>(w2);
#pragma unroll
        for (int p = 0; p < 8; ++p) {
            const int idx = tid + p * 256;           // = j*32 + c
            const int j = idx >> 5, c = idx & 31;
            w2s4[j * 32 + (c ^ (j & 7))] = w2v[idx];
        }
    }
    __syncthreads();

    // ---- loop-invariant per-lane parameters (BN folded to fma consts) ----
    const float4 aw  = *reinterpret_cast<const float4*>(attn_w + lane * 4);
    const float  ab  = attn_b[0];
    const float4 w1a = *reinterpret_cast<const float4*>(w1 + lane * 4);
    const float4 w1b = *reinterpret_cast<const float4*>(w1 + (lane + 64) * 4);
    const float  b1a = b1[lane], b1b = b1[lane + 64];
    const float  c1a = g1[lane] * (1.0f / sqrtf(v1[lane] + kEps));
    const float  c1b = g1[lane + 64] * (1.0f / sqrtf(v1[lane + 64] + kEps));
    const float  c0a = be1[lane] - m1[lane] * c1a;
    const float  c0b = be1[lane + 64] - m1[lane + 64] * c1b;
    const float  b2j = b2[lane];

    // head fold: dz_full = sum_j alpha_j*ReLU(pre_j) + C;  cls = dz_full > thr
    //   alpha_j = (w3[1,j]-w3[0,j]) * c12_j,  C = sum_j (w3diff_j * c02_j)
    float alpha, thrp;
    {
        const float wdj = w3[64 + lane] - w3[lane];
        const float c12 = g2[lane] * (1.0f / sqrtf(v2[lane] + kEps));
        const float c02 = be2[lane] - m2[lane] * c12;
        alpha = wdj * c12;
        const float C = lane_bcast(dpp_sum63(wdj * c02), 63);
        thrp = kLn3 - (b3[1] - b3[0]) - C;   // cls=1 iff sum alpha*ReLU(pre) > thrp
    }

    // 8 swizzled row base indices for this lane's w2 row (float4 units).
    int wofs[8];
#pragma unroll
    for (int m = 0; m < 8; ++m) wofs[m] = lane * 32 + (m ^ (lane & 7));

    const int b0 = wid * bpw;
    const float* xp = x    + (size_t)b0 * 1024 + lane * 4;
    const float* mp = mask + (size_t)b0 * 4;
    float*       rp = out_ret + (size_t)b0 * 256 + lane * 4;
    float*       wp = out_w   + (size_t)b0 * 4;
    float*       cp = out_cls + b0;

#pragma unroll 1
    for (int i = 0; i < bpw; i += 2) {
        // Stop LICM/CSE from hoisting the loop-invariant LDS w2 reads out of
        // the loop into 128 registers (spill hazard seen in R3).
        asm volatile("" ::: "memory");

        // ---- load pair of batches u=i, v=i+1 (8 coalesced b128 + 2 masks) ----
        const float4 xu0 = *reinterpret_cast<const float4*>(xp + 0);
        const float4 xu1 = *reinterpret_cast<const float4*>(xp + 256);
        const float4 xu2 = *reinterpret_cast<const float4*>(xp + 512);
        const float4 xu3 = *reinterpret_cast<const float4*>(xp + 768);
        const float4 xv0 = *reinterpret_cast<const float4*>(xp + 1024);
        const float4 xv1 = *reinterpret_cast<const float4*>(xp + 1280);
        const float4 xv2 = *reinterpret_cast<const float4*>(xp + 1536);
        const float4 xv3 = *reinterpret_cast<const float4*>(xp + 1792);
        const float4 mku = *reinterpret_cast<const float4*>(mp);
        const float4 mkv = *reinterpret_cast<const float4*>(mp + 4);

        // ---- attention scores (8 independent DPP chains, good ILP) ----
        float ru0 = dpp_sum63(dot4(xu0, aw));
        float ru1 = dpp_sum63(dot4(xu1, aw));
        float ru2 = dpp_sum63(dot4(xu2, aw));
        float ru3 = dpp_sum63(dot4(xu3, aw));
        float rv0 = dpp_sum63(dot4(xv0, aw));
        float rv1 = dpp_sum63(dot4(xv1, aw));
        float rv2 = dpp_sum63(dot4(xv2, aw));
        float rv3 = dpp_sum63(dot4(xv3, aw));
        const float au0 = fast_tanh(lane_bcast(ru0, 63) + ab) + mku.x;
        const float au1 = fast_tanh(lane_bcast(ru1, 63) + ab) + mku.y;
        const float au2 = fast_tanh(lane_bcast(ru2, 63) + ab) + mku.z;
        const float au3 = fast_tanh(lane_bcast(ru3, 63) + ab) + mku.w;
        const float av0 = fast_tanh(lane_bcast(rv0, 63) + ab) + mkv.x;
        const float av1 = fast_tanh(lane_bcast(rv1, 63) + ab) + mkv.y;
        const float av2 = fast_tanh(lane_bcast(rv2, 63) + ab) + mkv.z;
        const float av3 = fast_tanh(lane_bcast(rv3, 63) + ab) + mkv.w;

        // ---- softmax over 4 members, each batch ----
        const float umax = fmaxf(fmaxf(au0, au1), fmaxf(au2, au3));
        const float eu0 = __expf(au0 - umax), eu1 = __expf(au1 - umax);
        const float eu2 = __expf(au2 - umax), eu3 = __expf(au3 - umax);
        const float urs = 1.0f / (((eu0 + eu1) + eu2) + eu3);
        const float wtu0 = eu0 * urs, wtu1 = eu1 * urs, wtu2 = eu2 * urs, wtu3 = eu3 * urs;

        const float vmax = fmaxf(fmaxf(av0, av1), fmaxf(av2, av3));
        const float ev0 = __expf(av0 - vmax), ev1 = __expf(av1 - vmax);
        const float ev2 = __expf(av2 - vmax), ev3 = __expf(av3 - vmax);
        const float vrs = 1.0f / (((ev0 + ev1) + ev2) + ev3);
        const float wtv0 = ev0 * vrs, wtv1 = ev1 * vrs, wtv2 = ev2 * vrs, wtv3 = ev3 * vrs;

        // ---- layer 1: h1 = fma(relu(wf . w1row + b1), c1, c0) ----
        float pu = fmaf(wtu3, w1a.w, fmaf(wtu2, w1a.z, fmaf(wtu1, w1a.y, wtu0 * w1a.x))) + b1a;
        const float h1uA = fmaf(fmaxf(pu, 0.0f), c1a, c0a);
        pu = fmaf(wtu3, w1b.w, fmaf(wtu2, w1b.z, fmaf(wtu1, w1b.y, wtu0 * w1b.x))) + b1b;
        const float h1uB = fmaf(fmaxf(pu, 0.0f), c1b, c0b);
        float pv = fmaf(wtv3, w1a.w, fmaf(wtv2, w1a.z, fmaf(wtv1, w1a.y, wtv0 * w1a.x))) + b1a;
        const float h1vA = fmaf(fmaxf(pv, 0.0f), c1a, c0a);
        pv = fmaf(wtv3, w1b.w, fmaf(wtv2, w1b.z, fmaf(wtv1, w1b.y, wtv0 * w1b.x))) + b1b;
        const float h1vB = fmaf(fmaxf(pv, 0.0f), c1b, c0b);

        // ---- layer 2 matvec for BOTH batches: one w2 chunk read -> 8 fmacs.
        // h1 broadcast via v_readlane (VALU pipe; LDS pipe stays light). ----
        float accu0 = 0.0f, accu1 = 0.0f, accu2 = 0.0f, accu3 = 0.0f;
        float accv0 = 0.0f, accv1 = 0.0f, accv2 = 0.0f, accv3 = 0.0f;
#pragma unroll
        for (int c = 0; c < 32; ++c) {
            const float4 wv = w2s4[wofs[c & 7] + (c >> 3) * 8];
            const float srcU = (c < 16) ? h1uA : h1uB;
            const float srcV = (c < 16) ? h1vA : h1vB;
            const int l0 = (4 * c) & 63;
            accu0 = fmaf(lane_bcast(srcU, l0 + 0), wv.x, accu0);
            accu1 = fmaf(lane_bcast(srcU, l0 + 1), wv.y, accu1);
            accu2 = fmaf(lane_bcast(srcU, l0 + 2), wv.z, accu2);
            accu3 = fmaf(lane_bcast(srcU, l0 + 3), wv.w, accu3);
            accv0 = fmaf(lane_bcast(srcV, l0 + 0), wv.x, accv0);
            accv1 = fmaf(lane_bcast(srcV, l0 + 1), wv.y, accv1);
            accv2 = fmaf(lane_bcast(srcV, l0 + 2), wv.z, accv2);
            accv3 = fmaf(lane_bcast(srcV, l0 + 3), wv.w, accv3);
        }

        // ---- head: cls = [ sum_j alpha_j*ReLU(pre_j) > thrp ] ----
        const float preU = ((accu0 + accu1) + (accu2 + accu3)) + b2j;
        const float preV = ((accv0 + accv1) + (accv2 + accv3)) + b2j;
        float dzu = dpp_sum63(alpha * fmaxf(preU, 0.0f));
        float dzv = dpp_sum63(alpha * fmaxf(preV, 0.0f));
        const int clsU = (lane_bcast(dzu, 63) > thrp) ? 1 : 0;
        const int clsV = (lane_bcast(dzv, 63) > thrp) ? 1 : 0;

        // ---- batch u: argmax, pooling, store ----
        {
            int midx = 0; float mval = wtu0;
            if (wtu1 > mval) { mval = wtu1; midx = 1; }
            if (wtu2 > mval) { mval = wtu2; midx = 2; }
            if (wtu3 > mval) { mval = wtu3; midx = 3; }
            const float4 g01 = (midx == 1) ? xu1 : xu0;
            const float4 g23 = (midx == 3) ? xu3 : xu2;
            const float4 gth = (midx >= 2) ? g23 : g01;
            float4 pl;
            pl.x = fmaf(wtu3, xu3.x, fmaf(wtu2, xu2.x, fmaf(wtu1, xu1.x, wtu0 * xu0.x)));
            pl.y = fmaf(wtu3, xu3.y, fmaf(wtu2, xu2.y, fmaf(wtu1, xu1.y, wtu0 * xu0.y)));
            pl.z = fmaf(wtu3, xu3.z, fmaf(wtu2, xu2.z, fmaf(wtu1, xu1.z, wtu0 * xu0.z)));
            pl.w = fmaf(wtu3, xu3.w, fmaf(wtu2, xu2.w, fmaf(wtu1, xu1.w, wtu0 * xu0.w)));
            const float4 ret = (clsU == 1) ? gth : pl;
            *reinterpret_cast<float4*>(rp + (size_t)i * 256) = ret;
            if (lane == 0) {
                *reinterpret_cast<float4*>(wp + (size_t)i * 4) =
                    make_float4(wtu0, wtu1, wtu2, wtu3);
                cp[i] = (float)clsU;
            }
        }
        // ---- batch v: argmax, pooling, store ----
        {
            int midx = 0; float mval = wtv0;
            if (wtv1 > mval) { mval = wtv1; midx = 1; }
            if (wtv2 > mval) { mval = wtv2; midx = 2; }
            if (wtv3 > mval) { mval = wtv3; midx = 3; }
            const float4 g01 = (midx == 1) ? xv1 : xv0;
            const float4 g23 = (midx == 3) ? xv3 : xv2;
            const float4 gth = (midx >= 2) ? g23 : g01;
            float4 pl;
            pl.x = fmaf(wtv3, xv3.x, fmaf(wtv2, xv2.x, fmaf(wtv1, xv1.x, wtv0 * xv0.x)));
            pl.y = fmaf(wtv3, xv3.y, fmaf(wtv2, xv2.y, fmaf(wtv1, xv1.y, wtv0 * xv0.y)));
            pl.z = fmaf(wtv3, xv3.z, fmaf(wtv2, xv2.z, fmaf(wtv1, xv1.z, wtv0 * xv0.z)));
            pl.w = fmaf(wtv3, xv3.w, fmaf(wtv2, xv2.w, fmaf(wtv1, xv1.w, wtv0 * xv0.w)));
            const float4 ret = (clsV == 1) ? gth : pl;
            *reinterpret_cast<float4*>(rp + (size_t)(i + 1) * 256) = ret;
            if (lane == 0) {
                *reinterpret_cast<float4*>(wp + (size_t)(i + 1) * 4) =
                    make_float4(wtv0, wtv1, wtv2, wtv3);
                cp[i + 1] = (float)clsV;
            }
        }

        xp += 2048;
        mp += 8;
    }
}

extern "C" void kernel_launch(void* const* d_in, const int* in_sizes, int n_in,
                              void* d_out, int out_size, void* d_ws, size_t ws_size,
                              hipStream_t stream) {
    const float* x      = (const float*)d_in[0];
    const float* mask   = (const float*)d_in[1];
    const float* attn_w = (const float*)d_in[2];
    const float* attn_b = (const float*)d_in[3];
    const float* w1     = (const float*)d_in[4];
    const float* b1     = (const float*)d_in[5];
    const float* g1     = (const float*)d_in[6];
    const float* be1    = (const float*)d_in[7];
    const float* m1     = (const float*)d_in[8];
    const float* v1     = (const float*)d_in[9];
    const float* w2     = (const float*)d_in[10];
    const float* b2     = (const float*)d_in[11];
    const float* g2     = (const float*)d_in[12];
    const float* be2    = (const float*)d_in[13];
    const float* m2     = (const float*)d_in[14];
    const float* v2     = (const float*)d_in[15];
    const float* w3     = (const float*)d_in[16];
    const float* b3     = (const float*)d_in[17];

    float* out = (float*)d_out;
    float* out_ret = out;                         // [B, 256]
    float* out_w   = out + (size_t)262144 * 256;  // [B, 4, 1]
    float* out_cls = out_w + (size_t)262144 * 4;  // [B]

    const int threads = 256;                      // 4 waves/block
    const int blocks  = 4096;                     // 16384 waves total
    const int waves   = blocks * (threads / 64);
    const int bpw     = 262144 / waves;           // 16 batches/wave (8 pairs)

    agg_fused<<<blocks, threads, 0, stream>>>(
        x, mask, attn_w, attn_b, w1, b1, g1, be1, m1, v1,
        w2, b2, g2, be2, m2, v2, w3, b3,
        out_ret, out_w, out_cls, bpw);
}

// Round 11
// 251.294 us; speedup vs baseline: 2.2126x; 1.1474x over previous
//
#include <hip/hip_runtime.h>
#include <hip/hip_bf16.h>

// AttentionAggregator: fused one-pass kernel, round 11 = R10 retry with the
// nontemporal builtin fixed (it requires native clang vector types, not
// HIP_vector_type). Structure = R4/R9 (288us, reproducible) + two
// allocator-inert deltas:
//  1. Non-temporal loads for x / stores for out_ret (pure streaming data;
//     keeps 1.3GB of dead lines out of L2/MALL). Same instruction count and
//     registers -> zero spill risk.
//  2. Grid 4096 -> 8192 blocks (bpw 16 -> 8): smoother tail scheduling.

namespace {
constexpr float kEps = 1e-5f;
constexpr float kLn3 = 1.0986122886681098f;  // ln(3)
}

typedef float vfloat4 __attribute__((ext_vector_type(4)));

__device__ __forceinline__ float lane_bcast(float v, int srclane) {
    return __uint_as_float(__builtin_amdgcn_readlane(__float_as_uint(v), srclane));
}

template <int CTRL>
__device__ __forceinline__ float dpp_add(float x) {
    int s = __builtin_amdgcn_update_dpp(0, __float_as_int(x), CTRL, 0xF, 0xF, true);
    return x + __int_as_float(s);
}

// Full 64-lane sum on the VALU pipe; total lands in lane 63.
__device__ __forceinline__ float dpp_sum63(float x) {
    x = dpp_add<0x111>(x);  // row_shr:1
    x = dpp_add<0x112>(x);  // row_shr:2
    x = dpp_add<0x114>(x);  // row_shr:4
    x = dpp_add<0x118>(x);  // row_shr:8
    x = dpp_add<0x142>(x);  // row_bcast:15
    x = dpp_add<0x143>(x);  // row_bcast:31
    return x;
}

__device__ __forceinline__ float dot4(float4 a, float4 b) {
    return fmaf(a.w, b.w, fmaf(a.z, b.z, fmaf(a.y, b.y, a.x * b.x)));
}

// tanh(x) = 1 - 2/(e^{2x}+1); ~1e-6 rel err, saturates correctly.
__device__ __forceinline__ float fast_tanh(float x) {
    const float t = __expf(2.0f * x);
    return fmaf(-2.0f, __builtin_amdgcn_rcpf(t + 1.0f), 1.0f);
}

__device__ __forceinline__ float4 nt_load4(const float* p) {
    const vfloat4 v =
        __builtin_nontemporal_load(reinterpret_cast<const vfloat4*>(p));
    return make_float4(v.x, v.y, v.z, v.w);
}
__device__ __forceinline__ void nt_store4(float* p, float4 f) {
    vfloat4 v;
    v.x = f.x; v.y = f.y; v.z = f.z; v.w = f.w;
    __builtin_nontemporal_store(v, reinterpret_cast<vfloat4*>(p));
}

__global__ __launch_bounds__(256, 4) void agg_fused(
    const float* __restrict__ x, const float* __restrict__ mask,
    const float* __restrict__ attn_w, const float* __restrict__ attn_b,
    const float* __restrict__ w1, const float* __restrict__ b1,
    const float* __restrict__ g1, const float* __restrict__ be1,
    const float* __restrict__ m1, const float* __restrict__ v1,
    const float* __restrict__ w2, const float* __restrict__ b2,
    const float* __restrict__ g2, const float* __restrict__ be2,
    const float* __restrict__ m2, const float* __restrict__ v2,
    const float* __restrict__ w3, const float* __restrict__ b3,
    float* __restrict__ out_ret, float* __restrict__ out_w,
    float* __restrict__ out_cls, int bpw)
{
    // w2 tile, slot-XOR swizzled: element chunk (j, c) lives at
    // w2s4[j*32 + (c ^ (j&7))] -> a wave-wide ds_read_b128 of one chunk
    // column hits all 32 banks at the structural minimum.
    __shared__ float4 w2s4[64 * 32];

    const int tid  = threadIdx.x;
    const int lane = tid & 63;
    const int wid  = blockIdx.x * 4 + (tid >> 6);

    // ---- stage w2 into LDS (once per block, coalesced) ----
    {
        const float4* w2v = reinterpret_cast<const float4*>(w2);
#pragma unroll
        for (int p = 0; p < 8; ++p) {
            const int idx = tid + p * 256;           // = j*32 + c
            const int j = idx >> 5, c = idx & 31;
            w2s4[j * 32 + (c ^ (j & 7))] = w2v[idx];
        }
    }
    __syncthreads();

    // ---- loop-invariant per-lane parameters (BN folded to fma consts) ----
    const float4 aw  = *reinterpret_cast<const float4*>(attn_w + lane * 4);
    const float  ab  = attn_b[0];
    const float4 w1a = *reinterpret_cast<const float4*>(w1 + lane * 4);
    const float4 w1b = *reinterpret_cast<const float4*>(w1 + (lane + 64) * 4);
    const float  b1a = b1[lane], b1b = b1[lane + 64];
    const float  c1a = g1[lane] * (1.0f / sqrtf(v1[lane] + kEps));
    const float  c1b = g1[lane + 64] * (1.0f / sqrtf(v1[lane + 64] + kEps));
    const float  c0a = be1[lane] - m1[lane] * c1a;
    const float  c0b = be1[lane + 64] - m1[lane + 64] * c1b;
    const float  b2j = b2[lane];

    // head fold: dz_full = sum_j alpha_j*ReLU(pre_j) + C;  cls = dz_full > thr
    //   alpha_j = (w3[1,j]-w3[0,j]) * c12_j,  C = sum_j (w3diff_j * c02_j)
    float alpha, thrp;
    {
        const float wdj = w3[64 + lane] - w3[lane];
        const float c12 = g2[lane] * (1.0f / sqrtf(v2[lane] + kEps));
        const float c02 = be2[lane] - m2[lane] * c12;
        alpha = wdj * c12;
        const float C = lane_bcast(dpp_sum63(wdj * c02), 63);
        thrp = kLn3 - (b3[1] - b3[0]) - C;   // cls=1 iff sum alpha*ReLU(pre) > thrp
    }

    // 8 swizzled row base indices for this lane's w2 row (float4 units).
    int wofs[8];
#pragma unroll
    for (int m = 0; m < 8; ++m) wofs[m] = lane * 32 + (m ^ (lane & 7));

    const int b0 = wid * bpw;
    const float* xp = x    + (size_t)b0 * 1024 + lane * 4;
    const float* mp = mask + (size_t)b0 * 4;
    float*       rp = out_ret + (size_t)b0 * 256 + lane * 4;
    float*       wp = out_w   + (size_t)b0 * 4;
    float*       cp = out_cls + b0;

#pragma unroll 1
    for (int i = 0; i < bpw; i += 2) {
        // Stop LICM/CSE from hoisting the loop-invariant LDS w2 reads out of
        // the loop into 128 registers (spill hazard seen in R3).
        asm volatile("" ::: "memory");

        // ---- load pair of batches u=i, v=i+1 (8 coalesced nt b128 + masks) ----
        const float4 xu0 = nt_load4(xp + 0);
        const float4 xu1 = nt_load4(xp + 256);
        const float4 xu2 = nt_load4(xp + 512);
        const float4 xu3 = nt_load4(xp + 768);
        const float4 xv0 = nt_load4(xp + 1024);
        const float4 xv1 = nt_load4(xp + 1280);
        const float4 xv2 = nt_load4(xp + 1536);
        const float4 xv3 = nt_load4(xp + 1792);
        const float4 mku = *reinterpret_cast<const float4*>(mp);
        const float4 mkv = *reinterpret_cast<const float4*>(mp + 4);

        // ---- attention scores (8 independent DPP chains, good ILP) ----
        float ru0 = dpp_sum63(dot4(xu0, aw));
        float ru1 = dpp_sum63(dot4(xu1, aw));
        float ru2 = dpp_sum63(dot4(xu2, aw));
        float ru3 = dpp_sum63(dot4(xu3, aw));
        float rv0 = dpp_sum63(dot4(xv0, aw));
        float rv1 = dpp_sum63(dot4(xv1, aw));
        float rv2 = dpp_sum63(dot4(xv2, aw));
        float rv3 = dpp_sum63(dot4(xv3, aw));
        const float au0 = fast_tanh(lane_bcast(ru0, 63) + ab) + mku.x;
        const float au1 = fast_tanh(lane_bcast(ru1, 63) + ab) + mku.y;
        const float au2 = fast_tanh(lane_bcast(ru2, 63) + ab) + mku.z;
        const float au3 = fast_tanh(lane_bcast(ru3, 63) + ab) + mku.w;
        const float av0 = fast_tanh(lane_bcast(rv0, 63) + ab) + mkv.x;
        const float av1 = fast_tanh(lane_bcast(rv1, 63) + ab) + mkv.y;
        const float av2 = fast_tanh(lane_bcast(rv2, 63) + ab) + mkv.z;
        const float av3 = fast_tanh(lane_bcast(rv3, 63) + ab) + mkv.w;

        // ---- softmax over 4 members, each batch ----
        const float umax = fmaxf(fmaxf(au0, au1), fmaxf(au2, au3));
        const float eu0 = __expf(au0 - umax), eu1 = __expf(au1 - umax);
        const float eu2 = __expf(au2 - umax), eu3 = __expf(au3 - umax);
        const float urs = 1.0f / (((eu0 + eu1) + eu2) + eu3);
        const float wtu0 = eu0 * urs, wtu1 = eu1 * urs, wtu2 = eu2 * urs, wtu3 = eu3 * urs;

        const float vmax = fmaxf(fmaxf(av0, av1), fmaxf(av2, av3));
        const float ev0 = __expf(av0 - vmax), ev1 = __expf(av1 - vmax);
        const float ev2 = __expf(av2 - vmax), ev3 = __expf(av3 - vmax);
        const float vrs = 1.0f / (((ev0 + ev1) + ev2) + ev3);
        const float wtv0 = ev0 * vrs, wtv1 = ev1 * vrs, wtv2 = ev2 * vrs, wtv3 = ev3 * vrs;

        // ---- layer 1: h1 = fma(relu(wf . w1row + b1), c1, c0) ----
        float pu = fmaf(wtu3, w1a.w, fmaf(wtu2, w1a.z, fmaf(wtu1, w1a.y, wtu0 * w1a.x))) + b1a;
        const float h1uA = fmaf(fmaxf(pu, 0.0f), c1a, c0a);
        pu = fmaf(wtu3, w1b.w, fmaf(wtu2, w1b.z, fmaf(wtu1, w1b.y, wtu0 * w1b.x))) + b1b;
        const float h1uB = fmaf(fmaxf(pu, 0.0f), c1b, c0b);
        float pv = fmaf(wtv3, w1a.w, fmaf(wtv2, w1a.z, fmaf(wtv1, w1a.y, wtv0 * w1a.x))) + b1a;
        const float h1vA = fmaf(fmaxf(pv, 0.0f), c1a, c0a);
        pv = fmaf(wtv3, w1b.w, fmaf(wtv2, w1b.z, fmaf(wtv1, w1b.y, wtv0 * w1b.x))) + b1b;
        const float h1vB = fmaf(fmaxf(pv, 0.0f), c1b, c0b);

        // ---- layer 2 matvec for BOTH batches: one w2 chunk read -> 8 fmacs.
        // h1 broadcast via v_readlane (VALU pipe; LDS pipe stays light). ----
        float accu0 = 0.0f, accu1 = 0.0f, accu2 = 0.0f, accu3 = 0.0f;
        float accv0 = 0.0f, accv1 = 0.0f, accv2 = 0.0f, accv3 = 0.0f;
#pragma unroll
        for (int c = 0; c < 32; ++c) {
            const float4 wv = w2s4[wofs[c & 7] + (c >> 3) * 8];
            const float srcU = (c < 16) ? h1uA : h1uB;
            const float srcV = (c < 16) ? h1vA : h1vB;
            const int l0 = (4 * c) & 63;
            accu0 = fmaf(lane_bcast(srcU, l0 + 0), wv.x, accu0);
            accu1 = fmaf(lane_bcast(srcU, l0 + 1), wv.y, accu1);
            accu2 = fmaf(lane_bcast(srcU, l0 + 2), wv.z, accu2);
            accu3 = fmaf(lane_bcast(srcU, l0 + 3), wv.w, accu3);
            accv0 = fmaf(lane_bcast(srcV, l0 + 0), wv.x, accv0);
            accv1 = fmaf(lane_bcast(srcV, l0 + 1), wv.y, accv1);
            accv2 = fmaf(lane_bcast(srcV, l0 + 2), wv.z, accv2);
            accv3 = fmaf(lane_bcast(srcV, l0 + 3), wv.w, accv3);
        }

        // ---- head: cls = [ sum_j alpha_j*ReLU(pre_j) > thrp ] ----
        const float preU = ((accu0 + accu1) + (accu2 + accu3)) + b2j;
        const float preV = ((accv0 + accv1) + (accv2 + accv3)) + b2j;
        float dzu = dpp_sum63(alpha * fmaxf(preU, 0.0f));
        float dzv = dpp_sum63(alpha * fmaxf(preV, 0.0f));
        const int clsU = (lane_bcast(dzu, 63) > thrp) ? 1 : 0;
        const int clsV = (lane_bcast(dzv, 63) > thrp) ? 1 : 0;

        // ---- batch u: argmax, pooling, store ----
        {
            int midx = 0; float mval = wtu0;
            if (wtu1 > mval) { mval = wtu1; midx = 1; }
            if (wtu2 > mval) { mval = wtu2; midx = 2; }
            if (wtu3 > mval) { mval = wtu3; midx = 3; }
            const float4 g01 = (midx == 1) ? xu1 : xu0;
            const float4 g23 = (midx == 3) ? xu3 : xu2;
            const float4 gth = (midx >= 2) ? g23 : g01;
            float4 pl;
            pl.x = fmaf(wtu3, xu3.x, fmaf(wtu2, xu2.x, fmaf(wtu1, xu1.x, wtu0 * xu0.x)));
            pl.y = fmaf(wtu3, xu3.y, fmaf(wtu2, xu2.y, fmaf(wtu1, xu1.y, wtu0 * xu0.y)));
            pl.z = fmaf(wtu3, xu3.z, fmaf(wtu2, xu2.z, fmaf(wtu1, xu1.z, wtu0 * xu0.z)));
            pl.w = fmaf(wtu3, xu3.w, fmaf(wtu2, xu2.w, fmaf(wtu1, xu1.w, wtu0 * xu0.w)));
            const float4 ret = (clsU == 1) ? gth : pl;
            nt_store4(rp + (size_t)i * 256, ret);
            if (lane == 0) {
                *reinterpret_cast<float4*>(wp + (size_t)i * 4) =
                    make_float4(wtu0, wtu1, wtu2, wtu3);
                cp[i] = (float)clsU;
            }
        }
        // ---- batch v: argmax, pooling, store ----
        {
            int midx = 0; float mval = wtv0;
            if (wtv1 > mval) { mval = wtv1; midx = 1; }
            if (wtv2 > mval) { mval = wtv2; midx = 2; }
            if (wtv3 > mval) { mval = wtv3; midx = 3; }
            const float4 g01 = (midx == 1) ? xv1 : xv0;
            const float4 g23 = (midx == 3) ? xv3 : xv2;
            const float4 gth = (midx >= 2) ? g23 : g01;
            float4 pl;
            pl.x = fmaf(wtv3, xv3.x, fmaf(wtv2, xv2.x, fmaf(wtv1, xv1.x, wtv0 * xv0.x)));
            pl.y = fmaf(wtv3, xv3.y, fmaf(wtv2, xv2.y, fmaf(wtv1, xv1.y, wtv0 * xv0.y)));
            pl.z = fmaf(wtv3, xv3.z, fmaf(wtv2, xv2.z, fmaf(wtv1, xv1.z, wtv0 * xv0.z)));
            pl.w = fmaf(wtv3, xv3.w, fmaf(wtv2, xv2.w, fmaf(wtv1, xv1.w, wtv0 * xv0.w)));
            const float4 ret = (clsV == 1) ? gth : pl;
            nt_store4(rp + (size_t)(i + 1) * 256, ret);
            if (lane == 0) {
                *reinterpret_cast<float4*>(wp + (size_t)(i + 1) * 4) =
                    make_float4(wtv0, wtv1, wtv2, wtv3);
                cp[i + 1] = (float)clsV;
            }
        }

        xp += 2048;
        mp += 8;
    }
}

extern "C" void kernel_launch(void* const* d_in, const int* in_sizes, int n_in,
                              void* d_out, int out_size, void* d_ws, size_t ws_size,
                              hipStream_t stream) {
    const float* x      = (const float*)d_in[0];
    const float* mask   = (const float*)d_in[1];
    const float* attn_w = (const float*)d_in[2];
    const float* attn_b = (const float*)d_in[3];
    const float* w1     = (const float*)d_in[4];
    const float* b1     = (const float*)d_in[5];
    const float* g1     = (const float*)d_in[6];
    const float* be1    = (const float*)d_in[7];
    const float* m1     = (const float*)d_in[8];
    const float* v1     = (const float*)d_in[9];
    const float* w2     = (const float*)d_in[10];
    const float* b2     = (const float*)d_in[11];
    const float* g2     = (const float*)d_in[12];
    const float* be2    = (const float*)d_in[13];
    const float* m2     = (const float*)d_in[14];
    const float* v2     = (const float*)d_in[15];
    const float* w3     = (const float*)d_in[16];
    const float* b3     = (const float*)d_in[17];

    float* out = (float*)d_out;
    float* out_ret = out;                         // [B, 256]
    float* out_w   = out + (size_t)262144 * 256;  // [B, 4, 1]
    float* out_cls = out_w + (size_t)262144 * 4;  // [B]

    const int threads = 256;                      // 4 waves/block
    const int blocks  = 8192;                     // 32768 waves total
    const int waves   = blocks * (threads / 64);
    const int bpw     = 262144 / waves;           // 8 batches/wave (4 pairs)

    agg_fused<<<blocks, threads, 0, stream>>>(
        x, mask, attn_w, attn_b, w1, b1, g1, be1, m1, v1,
        w2, b2, g2, be2, m2, v2, w3, b3,
        out_ret, out_w, out_cls, bpw);
}